// Round 4
// baseline (442.196 us; speedup 1.0000x reference)
//
#include <hip/hip_runtime.h>

#define NNODES 100000
#define NEDGES 1600000
#define DIM    128
#define OUTD   32
#define NGRAPH 512

#define NBUCK2  256                          // bucket regions: dst >> 9
#define CAP     12288                        // per-bucket col capacity (mean 8192, +11 sigma)
#define NBUILD  ((NNODES + 511) / 512)       // 196 scan blocks
#define EBLOCKS ((NNODES + 63) / 64)         // 1563 (enc, M-tile 64)
#define AGGBLK  ((NNODES + 31) / 32)         // 3125 (exact: 3125*32 == 100000)
#define TBLOCKS ((NEDGES + 511) / 512)       // 3125 (edge-parallel kernels)

using bf16x8 = __attribute__((ext_vector_type(8))) short;
using f32x4  = __attribute__((ext_vector_type(4))) float;
using f32x2  = __attribute__((ext_vector_type(2))) float;

__device__ __forceinline__ short f2bf(float f) {
    unsigned u = __float_as_uint(f);
    unsigned r = (u + 0x7fff + ((u >> 16) & 1)) >> 16;   // RNE
    return (short)r;
}
__device__ __forceinline__ float bf2f(short s) {
    return __uint_as_float(((unsigned)(unsigned short)s) << 16);
}

// pack 8 bf16 -> 8 fp8 e4m3 bytes
__device__ __forceinline__ uint2 bf8_to_fp8(bf16x8 t) {
    float f0 = bf2f(t[0]), f1 = bf2f(t[1]), f2 = bf2f(t[2]), f3 = bf2f(t[3]);
    float f4 = bf2f(t[4]), f5 = bf2f(t[5]), f6 = bf2f(t[6]), f7 = bf2f(t[7]);
    uint2 o;
    o.x = __builtin_amdgcn_cvt_pk_fp8_f32(f0, f1, 0, false);
    o.x = __builtin_amdgcn_cvt_pk_fp8_f32(f2, f3, o.x, true);
    o.y = __builtin_amdgcn_cvt_pk_fp8_f32(f4, f5, 0, false);
    o.y = __builtin_amdgcn_cvt_pk_fp8_f32(f6, f7, o.y, true);
    return o;
}

// ============================================================
// Prep: weight transposes (bf16 W^T) + deg zero + pooled zero
// ============================================================
__global__ __launch_bounds__(256) void k_prep(
    const float* __restrict__ eW1, const float* __restrict__ eW2,
    const float* __restrict__ gW, short* __restrict__ WT,
    int* __restrict__ deg, float* __restrict__ pooled)
{
    int idx = blockIdx.x * 256 + threadIdx.x;
    if (idx < 5 * 16384) {
        int mat = idx >> 14, rem = idx & 16383;
        int k = rem >> 7, n = rem & 127;
        const float* src = (mat == 0) ? eW1 : (mat == 1) ? eW2
                                            : (gW + (size_t)(mat - 2) * 16384);
        WT[(size_t)mat * 16384 + n * DIM + k] = f2bf(src[k * DIM + n]);
    }
    if (idx < NNODES) deg[idx] = 0;
    if (idx < NGRAPH * DIM) pooled[idx] = 0.f;
}

// ============================================================
// CSR build v2: atomic degree count -> per-bucket scan -> atomic fill.
// Replaces reservation-scatter (2 kernels, 0.77 blocks/CU, 12.5MB tmp).
// ============================================================
__global__ __launch_bounds__(512) void k_deg(
    const int* __restrict__ dst, int* __restrict__ deg)
{
    int e = blockIdx.x * 512 + threadIdx.x;
    if (e < NEDGES) atomicAdd(&deg[dst[e]], 1);
}

__global__ __launch_bounds__(512) void k_scan(
    const int* __restrict__ deg, int* __restrict__ row_off,
    int* __restrict__ cur, float* __restrict__ inv)
{
    __shared__ int sc[512];
    const int b = blockIdx.x, t = threadIdx.x;
    const int node = b * 512 + t;
    const int d = (node < NNODES) ? deg[node] : 0;
    sc[t] = d;
    __syncthreads();
    for (int off = 1; off < 512; off <<= 1) {
        int v = (t >= off) ? sc[t - off] : 0;
        __syncthreads();
        sc[t] += v;
        __syncthreads();
    }
    const int start = b * CAP + sc[t] - d;   // bucketed layout: no global prefix
    if (node < NNODES) {
        row_off[node] = start;
        cur[node]     = start;
        inv[node]     = rsqrtf((float)d + 1.0f);
    }
}

__global__ __launch_bounds__(512) void k_fill(
    const int* __restrict__ src, const int* __restrict__ dst,
    int* __restrict__ cur, int* __restrict__ col)
{
    int e = blockIdx.x * 512 + threadIdx.x;
    if (e < NEDGES) {
        int d = dst[e];
        int pos = atomicAdd(&cur[d], 1);
        if (pos < ((d >> 9) + 1) * CAP)
            col[pos] = src[e] << 7;          // pre-shifted byte offset (src*128)
    }
}

// ============================================================
// Fused encoder v3: M-tile 64, swizzled unpadded LDS (48KB -> 3 blocks/CU).
// ============================================================
__global__ __launch_bounds__(512, 6) void k_enc(
    const float* __restrict__ x, const short* __restrict__ WT,
    const float* __restrict__ b1, const float* __restrict__ b2,
    const float* __restrict__ inv, unsigned char* __restrict__ g8, int M)
{
    __shared__ short As[64 * 128];     // 16 KB
    __shared__ short Bs[128 * 128];    // 32 KB

    const int tid = threadIdx.x;
    const int m0  = blockIdx.x * 64;

    // ---- stage x (fp32 -> bf16), swizzled ----
    #pragma unroll
    for (int i = 0; i < 2; ++i) {
        int u = tid + i * 512;
        int row = u >> 4, c = u & 15;
        int gr = min(m0 + row, M - 1);
        const float4* sp = (const float4*)(x + (size_t)gr * DIM + (c << 3));
        float4 f0 = sp[0], f1 = sp[1];
        short t8[8] = { f2bf(f0.x), f2bf(f0.y), f2bf(f0.z), f2bf(f0.w),
                        f2bf(f1.x), f2bf(f1.y), f2bf(f1.z), f2bf(f1.w) };
        *(bf16x8*)&As[row * 128 + ((c ^ (row & 15)) << 3)] = *(bf16x8*)t8;
    }

    const int wave = tid >> 6, lane = tid & 63;
    const int ml = lane & 15, quad = lane >> 4;
    const int rw = wave >> 1;    // row strip: rows rw*16..+16
    const int cw = wave & 1;     // col half:  cols cw*64..+64

    #pragma unroll
    for (int mat = 0; mat < 3; ++mat) {
        if (mat > 0) __syncthreads();
        // stage Bs[mat], swizzled
        #pragma unroll
        for (int i = 0; i < 4; ++i) {
            int u = tid + i * 512;
            int n = u >> 4, c = u & 15;
            *(bf16x8*)&Bs[n * 128 + ((c ^ (n & 15)) << 3)] =
                *(const bf16x8*)(WT + (size_t)mat * 16384 + n * DIM + (c << 3));
        }
        __syncthreads();   // covers As staging (mat=0), prior epilogues, Bs

        f32x4 acc[4] = {};
        const int arow = rw * 16 + ml;
        #pragma unroll
        for (int kk = 0; kk < 4; ++kk) {
            const int c = kk * 4 + quad;
            bf16x8 a = *(bf16x8*)&As[arow * 128 + ((c ^ (arow & 15)) << 3)];
            #pragma unroll
            for (int ni = 0; ni < 4; ++ni) {
                const int brow = (cw * 4 + ni) * 16 + ml;
                bf16x8 b = *(bf16x8*)&Bs[brow * 128 + ((c ^ (brow & 15)) << 3)];
                acc[ni] = __builtin_amdgcn_mfma_f32_16x16x32_bf16(a, b, acc[ni], 0, 0, 0);
            }
        }
        __syncthreads();   // partner wave may still be reading our rows

        #pragma unroll
        for (int ni = 0; ni < 4; ++ni) {
            const int colc = cw * 64 + ni * 16 + ml;
            const int cc = colc >> 3, w = colc & 7;
            #pragma unroll
            for (int r = 0; r < 4; ++r) {
                const int rowl = rw * 16 + quad * 4 + r;
                float v = acc[ni][r];
                if (mat == 0)      v = fmaxf(v + b1[colc], 0.f);
                else if (mat == 1) v = fmaxf(v + b2[colc], 0.f);
                else               v *= inv[min(m0 + rowl, M - 1)];
                As[rowl * 128 + (((cc ^ (rowl & 15)) << 3) | w)] = f2bf(v);
            }
        }
    }
    __syncthreads();

    // ---- store g as fp8, swizzled read ----
    #pragma unroll
    for (int i = 0; i < 2; ++i) {
        int u = tid + i * 512;
        int row = u >> 4, c = u & 15;
        int gr = m0 + row;
        if (gr < M) {
            bf16x8 t = *(bf16x8*)&As[row * 128 + ((c ^ (row & 15)) << 3)];
            *(uint2*)(g8 + (size_t)gr * DIM + (c << 3)) = bf8_to_fp8(t);
        }
    }
}

// ---- pipelined gather body (8 loads in flight DURING accumulation) ----
#define GATHER_PIPELINE(GBASE)                                                 \
    const int s = row_off[node];                                               \
    const int e = s + cntA[node];                                              \
    int j = s;                                                                 \
    {                                                                          \
        uint2 b0, b1_, b2_, b3_, b4_, b5_, b6_, b7_;                           \
        const bool hav = (j + 7 < e);                                          \
        if (hav) {                                                             \
            b0 = GLD(col[j]);     b1_ = GLD(col[j + 1]);                       \
            b2_ = GLD(col[j + 2]); b3_ = GLD(col[j + 3]);                      \
            b4_ = GLD(col[j + 4]); b5_ = GLD(col[j + 5]);                      \
            b6_ = GLD(col[j + 6]); b7_ = GLD(col[j + 7]);                      \
            j += 8;                                                            \
        }                                                                      \
        for (; j + 7 < e; j += 8) {                                            \
            uint2 n0 = GLD(col[j]);     uint2 n1 = GLD(col[j + 1]);            \
            uint2 n2 = GLD(col[j + 2]); uint2 n3 = GLD(col[j + 3]);            \
            uint2 n4 = GLD(col[j + 4]); uint2 n5 = GLD(col[j + 5]);            \
            uint2 n6 = GLD(col[j + 6]); uint2 n7 = GLD(col[j + 7]);            \
            ACC8(b0) ACC8(b1_) ACC8(b2_) ACC8(b3_)                             \
            ACC8(b4_) ACC8(b5_) ACC8(b6_) ACC8(b7_)                            \
            b0 = n0; b1_ = n1; b2_ = n2; b3_ = n3;                             \
            b4_ = n4; b5_ = n5; b6_ = n6; b7_ = n7;                            \
        }                                                                      \
        if (hav) {                                                             \
            ACC8(b0) ACC8(b1_) ACC8(b2_) ACC8(b3_)                             \
            ACC8(b4_) ACC8(b5_) ACC8(b6_) ACC8(b7_)                            \
        }                                                                      \
    }                                                                          \
    for (; j + 3 < e; j += 4) {                                                \
        uint2 v0 = GLD(col[j]);     uint2 v1 = GLD(col[j + 1]);                \
        uint2 v2 = GLD(col[j + 2]); uint2 v3 = GLD(col[j + 3]);                \
        ACC8(v0) ACC8(v1) ACC8(v2) ACC8(v3)                                    \
    }                                                                          \
    for (; j < e; ++j) {                                                       \
        uint2 v = GLD(col[j]);                                                 \
        ACC8(v)                                                                \
    }

// ============================================================
// Fused aggregation + GEMM (layers 0,1), pipelined gather.
// ============================================================
__global__ __launch_bounds__(512, 8) void k_agg_gemm(
    const unsigned char* __restrict__ g8v, const int* __restrict__ row_off,
    const int* __restrict__ cntA, const int* __restrict__ col,
    const float* __restrict__ inv, const float* __restrict__ bias,
    const short* __restrict__ WT, unsigned char* __restrict__ g8o)
{
    __shared__ short As[32 * 128];    //  8 KB
    __shared__ short Bs[128 * 128];   // 32 KB

    const int tid = threadIdx.x;

    // ---- stage W^T early (swizzled): drains under the long gather ----
    #pragma unroll
    for (int i = 0; i < 4; ++i) {
        int u = tid + i * 512;
        int n = u >> 4, c = u & 15;
        *(bf16x8*)&Bs[n * 128 + ((c ^ (n & 15)) << 3)] =
            *(const bf16x8*)(WT + n * DIM + (c << 3));
    }

    const int wave = tid >> 6, lane = tid & 63;
    const int q    = lane >> 4;       // quarter-wave
    const int sl   = lane & 15;
    const int sl8  = sl << 3;         // byte offset within row
    const int nl   = wave * 4 + q;    // local node 0..31
    const int m0   = blockIdx.x * 32;
    const int node = m0 + nl;

    // ---- aggregate fp8 rows ----
    f32x2 a01, a23, a45, a67;
    {
        uint2 us = *(const uint2*)(g8v + (size_t)node * 128 + sl8);
        a01 = __builtin_amdgcn_cvt_pk_f32_fp8(us.x, false);
        a23 = __builtin_amdgcn_cvt_pk_f32_fp8(us.x, true);
        a45 = __builtin_amdgcn_cvt_pk_f32_fp8(us.y, false);
        a67 = __builtin_amdgcn_cvt_pk_f32_fp8(us.y, true);
    }

    #define ACC8(v) \
        a01 += __builtin_amdgcn_cvt_pk_f32_fp8(v.x, false); \
        a23 += __builtin_amdgcn_cvt_pk_f32_fp8(v.x, true);  \
        a45 += __builtin_amdgcn_cvt_pk_f32_fp8(v.y, false); \
        a67 += __builtin_amdgcn_cvt_pk_f32_fp8(v.y, true);
    #define GLD(c) (*(const uint2*)(g8v + (size_t)(unsigned)((c) + sl8)))

    GATHER_PIPELINE(g8v)

    #undef ACC8
    #undef GLD

    const float scv = inv[node];
    const float4 bb0 = ((const float4*)bias)[sl * 2];
    const float4 bb1 = ((const float4*)bias)[sl * 2 + 1];
    short o[8];
    o[0] = f2bf(fmaxf(fmaf(a01[0], scv, bb0.x), 0.f));
    o[1] = f2bf(fmaxf(fmaf(a01[1], scv, bb0.y), 0.f));
    o[2] = f2bf(fmaxf(fmaf(a23[0], scv, bb0.z), 0.f));
    o[3] = f2bf(fmaxf(fmaf(a23[1], scv, bb0.w), 0.f));
    o[4] = f2bf(fmaxf(fmaf(a45[0], scv, bb1.x), 0.f));
    o[5] = f2bf(fmaxf(fmaf(a45[1], scv, bb1.y), 0.f));
    o[6] = f2bf(fmaxf(fmaf(a67[0], scv, bb1.z), 0.f));
    o[7] = f2bf(fmaxf(fmaf(a67[1], scv, bb1.w), 0.f));
    *(bf16x8*)&As[nl * 128 + ((sl ^ (nl & 15)) << 3)] = *(bf16x8*)o;
    __syncthreads();   // As tile + Bs weights complete

    // ---- GEMM: [32x128] @ W; wave -> (row-half, col-quad) ----
    const int mh = wave >> 2;   // 0..1 : rows mh*16..+16
    const int nq = wave & 3;    // 0..3 : cols nq*32..+32
    f32x4 acc[2] = {};
    #pragma unroll
    for (int kk = 0; kk < 4; ++kk) {
        const int c = kk * 4 + q;           // 16B chunk index
        bf16x8 a = *(bf16x8*)&As[(mh * 16 + sl) * 128 + ((c ^ sl) << 3)];
        #pragma unroll
        for (int ni = 0; ni < 2; ++ni) {
            bf16x8 b = *(bf16x8*)&Bs[((nq * 2 + ni) * 16 + sl) * 128 + ((c ^ sl) << 3)];
            acc[ni] = __builtin_amdgcn_mfma_f32_16x16x32_bf16(a, b, acc[ni], 0, 0, 0);
        }
    }
    __syncthreads();   // all fragment reads of As done before overwrite

    #pragma unroll
    for (int ni = 0; ni < 2; ++ni) {
        const int colc = (nq * 2 + ni) * 16 + sl;
        const int cc   = colc >> 3, cw = colc & 7;
        #pragma unroll
        for (int r = 0; r < 4; ++r) {
            const int rowl = mh * 16 + q * 4 + r;
            As[rowl * 128 + (((cc ^ (rowl & 15)) << 3) | cw)] =
                f2bf(acc[ni][r] * inv[m0 + rowl]);
        }
    }
    __syncthreads();

    // ---- store fp8: one uint2 per thread (32 rows x 16 slots) ----
    {
        int row = tid >> 4, c = tid & 15;
        bf16x8 t = *(bf16x8*)&As[row * 128 + ((c ^ (row & 15)) << 3)];
        *(uint2*)(g8o + (size_t)(m0 + row) * DIM + (c << 3)) = bf8_to_fp8(t);
    }
}

// ============================================================
// Fused aggregation + global add pool (last layer), pipelined gather.
// ============================================================
__global__ __launch_bounds__(512) void k_agg_pool(
    const unsigned char* __restrict__ g8v, const int* __restrict__ row_off,
    const int* __restrict__ cntA, const int* __restrict__ col,
    const float* __restrict__ inv, const float* __restrict__ bias,
    const int* __restrict__ batch, float* __restrict__ pooled)
{
    __shared__ float Hs[32][132];     // 16.9 KB fp32 tile (pad 4)
    __shared__ int sbatch[32];

    const int tid = threadIdx.x;
    const int wave = tid >> 6, lane = tid & 63;
    const int q    = lane >> 4;
    const int sl   = lane & 15;
    const int sl8  = sl << 3;
    const int nl   = wave * 4 + q;
    const int m0   = blockIdx.x * 32;
    const int node = m0 + nl;

    if (tid < 32) sbatch[tid] = batch[m0 + tid];

    f32x2 a01, a23, a45, a67;
    {
        uint2 us = *(const uint2*)(g8v + (size_t)node * 128 + sl8);
        a01 = __builtin_amdgcn_cvt_pk_f32_fp8(us.x, false);
        a23 = __builtin_amdgcn_cvt_pk_f32_fp8(us.x, true);
        a45 = __builtin_amdgcn_cvt_pk_f32_fp8(us.y, false);
        a67 = __builtin_amdgcn_cvt_pk_f32_fp8(us.y, true);
    }

    #define ACC8(v) \
        a01 += __builtin_amdgcn_cvt_pk_f32_fp8(v.x, false); \
        a23 += __builtin_amdgcn_cvt_pk_f32_fp8(v.x, true);  \
        a45 += __builtin_amdgcn_cvt_pk_f32_fp8(v.y, false); \
        a67 += __builtin_amdgcn_cvt_pk_f32_fp8(v.y, true);
    #define GLD(c) (*(const uint2*)(g8v + (size_t)(unsigned)((c) + sl8)))

    GATHER_PIPELINE(g8v)

    #undef ACC8
    #undef GLD

    const float scv = inv[node];
    const float4 bb0 = ((const float4*)bias)[sl * 2];
    const float4 bb1 = ((const float4*)bias)[sl * 2 + 1];
    float4 h0, h1;
    h0.x = fmaxf(fmaf(a01[0], scv, bb0.x), 0.f);
    h0.y = fmaxf(fmaf(a01[1], scv, bb0.y), 0.f);
    h0.z = fmaxf(fmaf(a23[0], scv, bb0.z), 0.f);
    h0.w = fmaxf(fmaf(a23[1], scv, bb0.w), 0.f);
    h1.x = fmaxf(fmaf(a45[0], scv, bb1.x), 0.f);
    h1.y = fmaxf(fmaf(a45[1], scv, bb1.y), 0.f);
    h1.z = fmaxf(fmaf(a67[0], scv, bb1.z), 0.f);
    h1.w = fmaxf(fmaf(a67[1], scv, bb1.w), 0.f);
    *(float4*)&Hs[nl][sl * 8]     = h0;
    *(float4*)&Hs[nl][sl * 8 + 4] = h1;
    __syncthreads();

    // ---- segmented reduce: thread = (group 0..3, dim 0..127) ----
    const int d   = tid & 127;
    const int grp = tid >> 7;
    float acc = 0.f;
    int cg = -1;
    #pragma unroll
    for (int i = 0; i < 8; ++i) {
        const int nn = grp * 8 + i;
        const int g  = sbatch[nn];
        if (g != cg) {
            if (cg >= 0) atomicAdd(pooled + (size_t)cg * DIM + d, acc);
            cg = g; acc = 0.f;
        }
        acc += Hs[nn][d];
    }
    atomicAdd(pooled + (size_t)cg * DIM + d, acc);
}

// ============================================================
// Decoder: one wave per graph (64 blocks x 8 waves).
// ============================================================
__global__ __launch_bounds__(512) void k_dec(
    const float* __restrict__ pooled, const float* __restrict__ W1,
    const float* __restrict__ b1, const float* __restrict__ W2,
    const float* __restrict__ b2, float* __restrict__ out)
{
    __shared__ float pbuf[8][128];
    __shared__ float tbuf[8][128];
    const int wave = threadIdx.x >> 6, lane = threadIdx.x & 63;
    const int g = blockIdx.x * 8 + wave;

    float2 pv = *(const float2*)(pooled + (size_t)g * DIM + lane * 2);
    pbuf[wave][lane * 2]     = pv.x;
    pbuf[wave][lane * 2 + 1] = pv.y;
    __syncthreads();

    float t0 = 0.f, t1 = 0.f;
    #pragma unroll 8
    for (int k = 0; k < DIM; ++k) {
        float pk = pbuf[wave][k];
        float2 w = *(const float2*)(W1 + (size_t)k * DIM + lane * 2);
        t0 = fmaf(pk, w.x, t0);
        t1 = fmaf(pk, w.y, t1);
    }
    tbuf[wave][lane * 2]     = fmaxf(t0 + b1[lane * 2],     0.f);
    tbuf[wave][lane * 2 + 1] = fmaxf(t1 + b1[lane * 2 + 1], 0.f);
    __syncthreads();

    const int c = lane & 31, hh = lane >> 5;
    float part = 0.f;
    #pragma unroll 8
    for (int kk = 0; kk < 64; ++kk) {
        int k = hh * 64 + kk;
        part = fmaf(tbuf[wave][k], W2[(size_t)k * OUTD + c], part);
    }
    float other = __shfl_xor(part, 32, 64);
    if (hh == 0)
        out[(size_t)g * OUTD + c] = part + other + b2[c];
}

// ============================================================
extern "C" void kernel_launch(void* const* d_in, const int* in_sizes, int n_in,
                              void* d_out, int out_size, void* d_ws, size_t ws_size,
                              hipStream_t stream)
{
    const float* x      = (const float*)d_in[0];
    const int*   ei     = (const int*)d_in[1];
    const int*   batch  = (const int*)d_in[2];
    const float* enc_W1 = (const float*)d_in[3];
    const float* enc_b1 = (const float*)d_in[4];
    const float* enc_W2 = (const float*)d_in[5];
    const float* enc_b2 = (const float*)d_in[6];
    const float* gcn_W  = (const float*)d_in[7];
    const float* gcn_b  = (const float*)d_in[8];
    const float* dec_W1 = (const float*)d_in[9];
    const float* dec_b1 = (const float*)d_in[10];
    const float* dec_W2 = (const float*)d_in[11];
    const float* dec_b2 = (const float*)d_in[12];
    float* out = (float*)d_out;

    const int* src = ei;
    const int* dst = ei + NEDGES;

    char* p = (char*)d_ws;
    auto alloc = [&](size_t bytes) -> void* {
        void* r = (void*)p;
        p += (bytes + 255) & ~(size_t)255;
        return r;
    };
    unsigned char* g8a    = (unsigned char*)alloc((size_t)NNODES * DIM);
    unsigned char* g8b    = (unsigned char*)alloc((size_t)NNODES * DIM);
    float*         inv    = (float*)        alloc((size_t)NNODES * sizeof(float));
    int*           row_off= (int*)          alloc((size_t)NNODES * sizeof(int));
    int*           deg    = (int*)          alloc((size_t)NNODES * sizeof(int));
    int*           cur    = (int*)          alloc((size_t)NNODES * sizeof(int));
    int*           col    = (int*)          alloc((size_t)NBUCK2 * CAP * sizeof(int));
    short*         WT     = (short*)        alloc((size_t)5 * DIM * DIM * sizeof(short));
    float*         pooled = (float*)        alloc((size_t)NGRAPH * DIM * sizeof(float));

    // ---- prep + CSR build (atomic count -> bucket scan -> atomic fill) ----
    k_prep <<<(NNODES + 255) / 256, 256, 0, stream>>>(enc_W1, enc_W2, gcn_W,
                                                      WT, deg, pooled);
    k_deg  <<<TBLOCKS, 512, 0, stream>>>(dst, deg);
    k_scan <<<NBUILD, 512, 0, stream>>>(deg, row_off, cur, inv);
    k_fill <<<TBLOCKS, 512, 0, stream>>>(src, dst, cur, col);

    // ---- fused encoder: x -> g0 (fp8, pre-scaled by inv) ----
    k_enc<<<EBLOCKS, 512, 0, stream>>>(x, WT, enc_b1, enc_b2, inv, g8a, NNODES);

    // ---- GCN layers: fused agg+gemm (ping-pong g8), last layer agg+pool ----
    k_agg_gemm<<<AGGBLK, 512, 0, stream>>>(g8a, row_off, deg, col, inv,
                                           gcn_b,       WT + 3 * 16384, g8b);
    k_agg_gemm<<<AGGBLK, 512, 0, stream>>>(g8b, row_off, deg, col, inv,
                                           gcn_b + 128, WT + 4 * 16384, g8a);
    k_agg_pool<<<AGGBLK, 512, 0, stream>>>(g8a, row_off, deg, col, inv,
                                           gcn_b + 256, batch, pooled);

    // ---- decoder ----
    k_dec <<<NGRAPH / 8, 512, 0, stream>>>(pooled, dec_W1, dec_b1,
                                           dec_W2, dec_b2, out);
}

// Round 5
// 290.885 us; speedup vs baseline: 1.5202x; 1.5202x over previous
//
#include <hip/hip_runtime.h>

#define NNODES 100000
#define NEDGES 1600000
#define DIM    128
#define OUTD   32
#define NGRAPH 512

#define NBUCK2  256                          // coarse buckets: dst >> 9
#define BSHIFT  9
#define CAP     12288                        // per-bucket region capacity (mean 8163)
#define EPB2    8192
#define SBLOCKS ((NEDGES + EPB2 - 1) / EPB2) // 196
#define NBUILD  ((NNODES + 511) / 512)       // 196
#define EBLOCKS ((NNODES + 63) / 64)         // 1563 (enc, M-tile 64)
#define AGGBLK  ((NNODES + 31) / 32)         // 3125 (exact: 3125*32 == 100000)

using bf16x8 = __attribute__((ext_vector_type(8))) short;
using f32x4  = __attribute__((ext_vector_type(4))) float;
using f32x2  = __attribute__((ext_vector_type(2))) float;

__device__ __forceinline__ short f2bf(float f) {
    unsigned u = __float_as_uint(f);
    unsigned r = (u + 0x7fff + ((u >> 16) & 1)) >> 16;   // RNE
    return (short)r;
}
__device__ __forceinline__ float bf2f(short s) {
    return __uint_as_float(((unsigned)(unsigned short)s) << 16);
}

// pack 8 bf16 -> 8 fp8 e4m3 bytes
__device__ __forceinline__ uint2 bf8_to_fp8(bf16x8 t) {
    float f0 = bf2f(t[0]), f1 = bf2f(t[1]), f2 = bf2f(t[2]), f3 = bf2f(t[3]);
    float f4 = bf2f(t[4]), f5 = bf2f(t[5]), f6 = bf2f(t[6]), f7 = bf2f(t[7]);
    uint2 o;
    o.x = __builtin_amdgcn_cvt_pk_fp8_f32(f0, f1, 0, false);
    o.x = __builtin_amdgcn_cvt_pk_fp8_f32(f2, f3, o.x, true);
    o.y = __builtin_amdgcn_cvt_pk_fp8_f32(f4, f5, 0, false);
    o.y = __builtin_amdgcn_cvt_pk_fp8_f32(f6, f7, o.y, true);
    return o;
}

// ============================================================
// Prep: weight transposes (bf16 W^T) + cursor init + pooled zero
// ============================================================
__global__ __launch_bounds__(256) void k_prep(
    const float* __restrict__ eW1, const float* __restrict__ eW2,
    const float* __restrict__ gW, short* __restrict__ WT,
    int* __restrict__ gcur, float* __restrict__ pooled)
{
    int idx = blockIdx.x * 256 + threadIdx.x;
    if (idx < 5 * 16384) {
        int mat = idx >> 14, rem = idx & 16383;
        int k = rem >> 7, n = rem & 127;
        const float* src = (mat == 0) ? eW1 : (mat == 1) ? eW2
                                            : (gW + (size_t)(mat - 2) * 16384);
        WT[(size_t)mat * 16384 + n * DIM + k] = f2bf(src[k * DIM + n]);
    }
    if (idx < NBUCK2) gcur[idx] = idx * CAP;
    if (idx < NGRAPH * DIM) pooled[idx] = 0.f;
}

// ============================================================
// CSR build — R3 reservation-scatter version (R4's atomic k_fill was
// 127us: random single-dword scatter writes cost a full line each,
// WRITE_SIZE 105MB. Reverted.)
// ============================================================
__global__ __launch_bounds__(512) void k_scatter(
    const int* __restrict__ src, const int* __restrict__ dst,
    int* __restrict__ gcur, unsigned* __restrict__ tmp)
{
    __shared__ unsigned short rnk[EPB2];
    __shared__ int h[NBUCK2];
    __shared__ int gbase[NBUCK2];
    const int tid  = threadIdx.x;
    const int base = blockIdx.x * EPB2;
    if (tid < NBUCK2) h[tid] = 0;
    __syncthreads();
    #pragma unroll
    for (int it = 0; it < EPB2 / 512; ++it) {
        int e = base + it * 512 + tid;
        if (e < NEDGES) {
            int b = dst[e] >> BSHIFT;
            rnk[it * 512 + tid] = (unsigned short)atomicAdd(&h[b], 1);
        }
    }
    __syncthreads();
    if (tid < NBUCK2 && h[tid] > 0)
        gbase[tid] = atomicAdd(&gcur[tid], h[tid]);
    __syncthreads();
    #pragma unroll
    for (int it = 0; it < EPB2 / 512; ++it) {
        int e = base + it * 512 + tid;
        if (e < NEDGES) {
            int d = dst[e], sv = src[e];
            int b = d >> BSHIFT;
            int pos = gbase[b] + rnk[it * 512 + tid];
            if (pos < (b + 1) * CAP)
                tmp[pos] = (unsigned)sv | ((unsigned)(d & 511) << 17);
        }
    }
}

__global__ __launch_bounds__(512) void k_build(
    const unsigned* __restrict__ tmp, const int* __restrict__ gcur,
    int* __restrict__ row_off, int* __restrict__ cntA,
    float* __restrict__ inv, int* __restrict__ col)
{
    __shared__ int hist[512], sc[512], lcur[512];
    const int tid   = threadIdx.x;
    const int b     = blockIdx.x;
    const int tbase = b * CAP;
    const int cnt_b = min(gcur[b] - tbase, CAP);
    hist[tid] = 0;
    __syncthreads();
    for (int i = tid; i < cnt_b; i += 512)
        atomicAdd(&hist[(tmp[tbase + i] >> 17) & 511], 1);
    __syncthreads();
    const int hv = hist[tid];
    sc[tid] = hv;
    __syncthreads();
    for (int off = 1; off < 512; off <<= 1) {
        int t = (tid >= off) ? sc[tid - off] : 0;
        __syncthreads();
        sc[tid] += t;
        __syncthreads();
    }
    const int start = tbase + sc[tid] - hv;
    lcur[tid] = start;
    const int node = b * 512 + tid;
    if (node < NNODES) {
        row_off[node] = start;
        cntA[node]    = hv;
        inv[node]     = rsqrtf((float)hv + 1.0f);
    }
    __syncthreads();
    for (int i = tid; i < cnt_b; i += 512) {
        unsigned t = tmp[tbase + i];
        int pos = atomicAdd(&lcur[(t >> 17) & 511], 1);
        col[pos] = (int)((t & 0x1FFFFu) << 7);   // pre-shifted BYTE offset (src*128)
    }
}

// ============================================================
// Fused encoder v3: M-tile 64, swizzled unpadded LDS (48KB -> 3 blocks/CU).
// ============================================================
__global__ __launch_bounds__(512, 6) void k_enc(
    const float* __restrict__ x, const short* __restrict__ WT,
    const float* __restrict__ b1, const float* __restrict__ b2,
    const float* __restrict__ inv, unsigned char* __restrict__ g8, int M)
{
    __shared__ short As[64 * 128];     // 16 KB
    __shared__ short Bs[128 * 128];    // 32 KB

    const int tid = threadIdx.x;
    const int m0  = blockIdx.x * 64;

    // ---- stage x (fp32 -> bf16), swizzled ----
    #pragma unroll
    for (int i = 0; i < 2; ++i) {
        int u = tid + i * 512;
        int row = u >> 4, c = u & 15;
        int gr = min(m0 + row, M - 1);
        const float4* sp = (const float4*)(x + (size_t)gr * DIM + (c << 3));
        float4 f0 = sp[0], f1 = sp[1];
        short t8[8] = { f2bf(f0.x), f2bf(f0.y), f2bf(f0.z), f2bf(f0.w),
                        f2bf(f1.x), f2bf(f1.y), f2bf(f1.z), f2bf(f1.w) };
        *(bf16x8*)&As[row * 128 + ((c ^ (row & 15)) << 3)] = *(bf16x8*)t8;
    }

    const int wave = tid >> 6, lane = tid & 63;
    const int ml = lane & 15, quad = lane >> 4;
    const int rw = wave >> 1;    // row strip: rows rw*16..+16
    const int cw = wave & 1;     // col half:  cols cw*64..+64

    #pragma unroll
    for (int mat = 0; mat < 3; ++mat) {
        if (mat > 0) __syncthreads();
        // stage Bs[mat], swizzled
        #pragma unroll
        for (int i = 0; i < 4; ++i) {
            int u = tid + i * 512;
            int n = u >> 4, c = u & 15;
            *(bf16x8*)&Bs[n * 128 + ((c ^ (n & 15)) << 3)] =
                *(const bf16x8*)(WT + (size_t)mat * 16384 + n * DIM + (c << 3));
        }
        __syncthreads();   // covers As staging (mat=0), prior epilogues, Bs

        f32x4 acc[4] = {};
        const int arow = rw * 16 + ml;
        #pragma unroll
        for (int kk = 0; kk < 4; ++kk) {
            const int c = kk * 4 + quad;
            bf16x8 a = *(bf16x8*)&As[arow * 128 + ((c ^ (arow & 15)) << 3)];
            #pragma unroll
            for (int ni = 0; ni < 4; ++ni) {
                const int brow = (cw * 4 + ni) * 16 + ml;
                bf16x8 b = *(bf16x8*)&Bs[brow * 128 + ((c ^ (brow & 15)) << 3)];
                acc[ni] = __builtin_amdgcn_mfma_f32_16x16x32_bf16(a, b, acc[ni], 0, 0, 0);
            }
        }
        __syncthreads();   // partner wave may still be reading our rows

        #pragma unroll
        for (int ni = 0; ni < 4; ++ni) {
            const int colc = cw * 64 + ni * 16 + ml;
            const int cc = colc >> 3, w = colc & 7;
            #pragma unroll
            for (int r = 0; r < 4; ++r) {
                const int rowl = rw * 16 + quad * 4 + r;
                float v = acc[ni][r];
                if (mat == 0)      v = fmaxf(v + b1[colc], 0.f);
                else if (mat == 1) v = fmaxf(v + b2[colc], 0.f);
                else               v *= inv[min(m0 + rowl, M - 1)];
                As[rowl * 128 + (((cc ^ (rowl & 15)) << 3) | w)] = f2bf(v);
            }
        }
    }
    __syncthreads();

    // ---- store g as fp8, swizzled read ----
    #pragma unroll
    for (int i = 0; i < 2; ++i) {
        int u = tid + i * 512;
        int row = u >> 4, c = u & 15;
        int gr = m0 + row;
        if (gr < M) {
            bf16x8 t = *(bf16x8*)&As[row * 128 + ((c ^ (row & 15)) << 3)];
            *(uint2*)(g8 + (size_t)gr * DIM + (c << 3)) = bf8_to_fp8(t);
        }
    }
}

// ---- pipelined gather body (8 loads in flight DURING accumulation) ----
#define GATHER_PIPELINE()                                                      \
    const int s = row_off[node];                                               \
    const int e = s + cntA[node];                                              \
    int j = s;                                                                 \
    {                                                                          \
        uint2 b0, b1_, b2_, b3_, b4_, b5_, b6_, b7_;                           \
        const bool hav = (j + 7 < e);                                          \
        if (hav) {                                                             \
            b0 = GLD(col[j]);     b1_ = GLD(col[j + 1]);                       \
            b2_ = GLD(col[j + 2]); b3_ = GLD(col[j + 3]);                      \
            b4_ = GLD(col[j + 4]); b5_ = GLD(col[j + 5]);                      \
            b6_ = GLD(col[j + 6]); b7_ = GLD(col[j + 7]);                      \
            j += 8;                                                            \
        }                                                                      \
        for (; j + 7 < e; j += 8) {                                            \
            uint2 n0 = GLD(col[j]);     uint2 n1 = GLD(col[j + 1]);            \
            uint2 n2 = GLD(col[j + 2]); uint2 n3 = GLD(col[j + 3]);            \
            uint2 n4 = GLD(col[j + 4]); uint2 n5 = GLD(col[j + 5]);            \
            uint2 n6 = GLD(col[j + 6]); uint2 n7 = GLD(col[j + 7]);            \
            ACC8(b0) ACC8(b1_) ACC8(b2_) ACC8(b3_)                             \
            ACC8(b4_) ACC8(b5_) ACC8(b6_) ACC8(b7_)                            \
            b0 = n0; b1_ = n1; b2_ = n2; b3_ = n3;                             \
            b4_ = n4; b5_ = n5; b6_ = n6; b7_ = n7;                            \
        }                                                                      \
        if (hav) {                                                             \
            ACC8(b0) ACC8(b1_) ACC8(b2_) ACC8(b3_)                             \
            ACC8(b4_) ACC8(b5_) ACC8(b6_) ACC8(b7_)                            \
        }                                                                      \
    }                                                                          \
    for (; j + 3 < e; j += 4) {                                                \
        uint2 v0 = GLD(col[j]);     uint2 v1 = GLD(col[j + 1]);                \
        uint2 v2 = GLD(col[j + 2]); uint2 v3 = GLD(col[j + 3]);                \
        ACC8(v0) ACC8(v1) ACC8(v2) ACC8(v3)                                    \
    }                                                                          \
    for (; j < e; ++j) {                                                       \
        uint2 v = GLD(col[j]);                                                 \
        ACC8(v)                                                                \
    }

// ============================================================
// Fused aggregation + GEMM (layers 0,1), pipelined gather.
// ============================================================
__global__ __launch_bounds__(512, 8) void k_agg_gemm(
    const unsigned char* __restrict__ g8v, const int* __restrict__ row_off,
    const int* __restrict__ cntA, const int* __restrict__ col,
    const float* __restrict__ inv, const float* __restrict__ bias,
    const short* __restrict__ WT, unsigned char* __restrict__ g8o)
{
    __shared__ short As[32 * 128];    //  8 KB
    __shared__ short Bs[128 * 128];   // 32 KB

    const int tid = threadIdx.x;

    // ---- stage W^T early (swizzled): drains under the long gather ----
    #pragma unroll
    for (int i = 0; i < 4; ++i) {
        int u = tid + i * 512;
        int n = u >> 4, c = u & 15;
        *(bf16x8*)&Bs[n * 128 + ((c ^ (n & 15)) << 3)] =
            *(const bf16x8*)(WT + n * DIM + (c << 3));
    }

    const int wave = tid >> 6, lane = tid & 63;
    const int q    = lane >> 4;       // quarter-wave
    const int sl   = lane & 15;
    const int sl8  = sl << 3;         // byte offset within row
    const int nl   = wave * 4 + q;    // local node 0..31
    const int m0   = blockIdx.x * 32;
    const int node = m0 + nl;

    // ---- aggregate fp8 rows ----
    f32x2 a01, a23, a45, a67;
    {
        uint2 us = *(const uint2*)(g8v + (size_t)node * 128 + sl8);
        a01 = __builtin_amdgcn_cvt_pk_f32_fp8(us.x, false);
        a23 = __builtin_amdgcn_cvt_pk_f32_fp8(us.x, true);
        a45 = __builtin_amdgcn_cvt_pk_f32_fp8(us.y, false);
        a67 = __builtin_amdgcn_cvt_pk_f32_fp8(us.y, true);
    }

    #define ACC8(v) \
        a01 += __builtin_amdgcn_cvt_pk_f32_fp8(v.x, false); \
        a23 += __builtin_amdgcn_cvt_pk_f32_fp8(v.x, true);  \
        a45 += __builtin_amdgcn_cvt_pk_f32_fp8(v.y, false); \
        a67 += __builtin_amdgcn_cvt_pk_f32_fp8(v.y, true);
    #define GLD(c) (*(const uint2*)(g8v + (size_t)(unsigned)((c) + sl8)))

    GATHER_PIPELINE()

    #undef ACC8
    #undef GLD

    const float scv = inv[node];
    const float4 bb0 = ((const float4*)bias)[sl * 2];
    const float4 bb1 = ((const float4*)bias)[sl * 2 + 1];
    short o[8];
    o[0] = f2bf(fmaxf(fmaf(a01[0], scv, bb0.x), 0.f));
    o[1] = f2bf(fmaxf(fmaf(a01[1], scv, bb0.y), 0.f));
    o[2] = f2bf(fmaxf(fmaf(a23[0], scv, bb0.z), 0.f));
    o[3] = f2bf(fmaxf(fmaf(a23[1], scv, bb0.w), 0.f));
    o[4] = f2bf(fmaxf(fmaf(a45[0], scv, bb1.x), 0.f));
    o[5] = f2bf(fmaxf(fmaf(a45[1], scv, bb1.y), 0.f));
    o[6] = f2bf(fmaxf(fmaf(a67[0], scv, bb1.z), 0.f));
    o[7] = f2bf(fmaxf(fmaf(a67[1], scv, bb1.w), 0.f));
    *(bf16x8*)&As[nl * 128 + ((sl ^ (nl & 15)) << 3)] = *(bf16x8*)o;
    __syncthreads();   // As tile + Bs weights complete

    // ---- GEMM: [32x128] @ W; wave -> (row-half, col-quad) ----
    const int mh = wave >> 2;   // 0..1 : rows mh*16..+16
    const int nq = wave & 3;    // 0..3 : cols nq*32..+32
    f32x4 acc[2] = {};
    #pragma unroll
    for (int kk = 0; kk < 4; ++kk) {
        const int c = kk * 4 + q;           // 16B chunk index
        bf16x8 a = *(bf16x8*)&As[(mh * 16 + sl) * 128 + ((c ^ sl) << 3)];
        #pragma unroll
        for (int ni = 0; ni < 2; ++ni) {
            bf16x8 b = *(bf16x8*)&Bs[((nq * 2 + ni) * 16 + sl) * 128 + ((c ^ sl) << 3)];
            acc[ni] = __builtin_amdgcn_mfma_f32_16x16x32_bf16(a, b, acc[ni], 0, 0, 0);
        }
    }
    __syncthreads();   // all fragment reads of As done before overwrite

    #pragma unroll
    for (int ni = 0; ni < 2; ++ni) {
        const int colc = (nq * 2 + ni) * 16 + sl;
        const int cc   = colc >> 3, cw = colc & 7;
        #pragma unroll
        for (int r = 0; r < 4; ++r) {
            const int rowl = mh * 16 + q * 4 + r;
            As[rowl * 128 + (((cc ^ (rowl & 15)) << 3) | cw)] =
                f2bf(acc[ni][r] * inv[m0 + rowl]);
        }
    }
    __syncthreads();

    // ---- store fp8: one uint2 per thread (32 rows x 16 slots) ----
    {
        int row = tid >> 4, c = tid & 15;
        bf16x8 t = *(bf16x8*)&As[row * 128 + ((c ^ (row & 15)) << 3)];
        *(uint2*)(g8o + (size_t)(m0 + row) * DIM + (c << 3)) = bf8_to_fp8(t);
    }
}

// ============================================================
// Fused aggregation + global add pool (last layer), pipelined gather.
// ============================================================
__global__ __launch_bounds__(512) void k_agg_pool(
    const unsigned char* __restrict__ g8v, const int* __restrict__ row_off,
    const int* __restrict__ cntA, const int* __restrict__ col,
    const float* __restrict__ inv, const float* __restrict__ bias,
    const int* __restrict__ batch, float* __restrict__ pooled)
{
    __shared__ float Hs[32][132];     // 16.9 KB fp32 tile (pad 4)
    __shared__ int sbatch[32];

    const int tid = threadIdx.x;
    const int wave = tid >> 6, lane = tid & 63;
    const int q    = lane >> 4;
    const int sl   = lane & 15;
    const int sl8  = sl << 3;
    const int nl   = wave * 4 + q;
    const int m0   = blockIdx.x * 32;
    const int node = m0 + nl;

    if (tid < 32) sbatch[tid] = batch[m0 + tid];

    f32x2 a01, a23, a45, a67;
    {
        uint2 us = *(const uint2*)(g8v + (size_t)node * 128 + sl8);
        a01 = __builtin_amdgcn_cvt_pk_f32_fp8(us.x, false);
        a23 = __builtin_amdgcn_cvt_pk_f32_fp8(us.x, true);
        a45 = __builtin_amdgcn_cvt_pk_f32_fp8(us.y, false);
        a67 = __builtin_amdgcn_cvt_pk_f32_fp8(us.y, true);
    }

    #define ACC8(v) \
        a01 += __builtin_amdgcn_cvt_pk_f32_fp8(v.x, false); \
        a23 += __builtin_amdgcn_cvt_pk_f32_fp8(v.x, true);  \
        a45 += __builtin_amdgcn_cvt_pk_f32_fp8(v.y, false); \
        a67 += __builtin_amdgcn_cvt_pk_f32_fp8(v.y, true);
    #define GLD(c) (*(const uint2*)(g8v + (size_t)(unsigned)((c) + sl8)))

    GATHER_PIPELINE()

    #undef ACC8
    #undef GLD

    const float scv = inv[node];
    const float4 bb0 = ((const float4*)bias)[sl * 2];
    const float4 bb1 = ((const float4*)bias)[sl * 2 + 1];
    float4 h0, h1;
    h0.x = fmaxf(fmaf(a01[0], scv, bb0.x), 0.f);
    h0.y = fmaxf(fmaf(a01[1], scv, bb0.y), 0.f);
    h0.z = fmaxf(fmaf(a23[0], scv, bb0.z), 0.f);
    h0.w = fmaxf(fmaf(a23[1], scv, bb0.w), 0.f);
    h1.x = fmaxf(fmaf(a45[0], scv, bb1.x), 0.f);
    h1.y = fmaxf(fmaf(a45[1], scv, bb1.y), 0.f);
    h1.z = fmaxf(fmaf(a67[0], scv, bb1.z), 0.f);
    h1.w = fmaxf(fmaf(a67[1], scv, bb1.w), 0.f);
    *(float4*)&Hs[nl][sl * 8]     = h0;
    *(float4*)&Hs[nl][sl * 8 + 4] = h1;
    __syncthreads();

    // ---- segmented reduce: thread = (group 0..3, dim 0..127) ----
    const int d   = tid & 127;
    const int grp = tid >> 7;
    float acc = 0.f;
    int cg = -1;
    #pragma unroll
    for (int i = 0; i < 8; ++i) {
        const int nn = grp * 8 + i;
        const int g  = sbatch[nn];
        if (g != cg) {
            if (cg >= 0) atomicAdd(pooled + (size_t)cg * DIM + d, acc);
            cg = g; acc = 0.f;
        }
        acc += Hs[nn][d];
    }
    atomicAdd(pooled + (size_t)cg * DIM + d, acc);
}

// ============================================================
// Decoder: one wave per graph (64 blocks x 8 waves).
// ============================================================
__global__ __launch_bounds__(512) void k_dec(
    const float* __restrict__ pooled, const float* __restrict__ W1,
    const float* __restrict__ b1, const float* __restrict__ W2,
    const float* __restrict__ b2, float* __restrict__ out)
{
    __shared__ float pbuf[8][128];
    __shared__ float tbuf[8][128];
    const int wave = threadIdx.x >> 6, lane = threadIdx.x & 63;
    const int g = blockIdx.x * 8 + wave;

    float2 pv = *(const float2*)(pooled + (size_t)g * DIM + lane * 2);
    pbuf[wave][lane * 2]     = pv.x;
    pbuf[wave][lane * 2 + 1] = pv.y;
    __syncthreads();

    float t0 = 0.f, t1 = 0.f;
    #pragma unroll 8
    for (int k = 0; k < DIM; ++k) {
        float pk = pbuf[wave][k];
        float2 w = *(const float2*)(W1 + (size_t)k * DIM + lane * 2);
        t0 = fmaf(pk, w.x, t0);
        t1 = fmaf(pk, w.y, t1);
    }
    tbuf[wave][lane * 2]     = fmaxf(t0 + b1[lane * 2],     0.f);
    tbuf[wave][lane * 2 + 1] = fmaxf(t1 + b1[lane * 2 + 1], 0.f);
    __syncthreads();

    const int c = lane & 31, hh = lane >> 5;
    float part = 0.f;
    #pragma unroll 8
    for (int kk = 0; kk < 64; ++kk) {
        int k = hh * 64 + kk;
        part = fmaf(tbuf[wave][k], W2[(size_t)k * OUTD + c], part);
    }
    float other = __shfl_xor(part, 32, 64);
    if (hh == 0)
        out[(size_t)g * OUTD + c] = part + other + b2[c];
}

// ============================================================
extern "C" void kernel_launch(void* const* d_in, const int* in_sizes, int n_in,
                              void* d_out, int out_size, void* d_ws, size_t ws_size,
                              hipStream_t stream)
{
    const float* x      = (const float*)d_in[0];
    const int*   ei     = (const int*)d_in[1];
    const int*   batch  = (const int*)d_in[2];
    const float* enc_W1 = (const float*)d_in[3];
    const float* enc_b1 = (const float*)d_in[4];
    const float* enc_W2 = (const float*)d_in[5];
    const float* enc_b2 = (const float*)d_in[6];
    const float* gcn_W  = (const float*)d_in[7];
    const float* gcn_b  = (const float*)d_in[8];
    const float* dec_W1 = (const float*)d_in[9];
    const float* dec_b1 = (const float*)d_in[10];
    const float* dec_W2 = (const float*)d_in[11];
    const float* dec_b2 = (const float*)d_in[12];
    float* out = (float*)d_out;

    const int* src = ei;
    const int* dst = ei + NEDGES;

    char* p = (char*)d_ws;
    auto alloc = [&](size_t bytes) -> void* {
        void* r = (void*)p;
        p += (bytes + 255) & ~(size_t)255;
        return r;
    };
    unsigned char* g8a    = (unsigned char*)alloc((size_t)NNODES * DIM);
    unsigned char* g8b    = (unsigned char*)alloc((size_t)NNODES * DIM);
    float*         inv    = (float*)        alloc((size_t)NNODES * sizeof(float));
    int*           row_off= (int*)          alloc((size_t)NNODES * sizeof(int));
    int*           cntA   = (int*)          alloc((size_t)NNODES * sizeof(int));
    int*           col    = (int*)          alloc((size_t)NBUCK2 * CAP * sizeof(int));
    unsigned*      tmp    = (unsigned*)     alloc((size_t)NBUCK2 * CAP * sizeof(unsigned));
    int*           gcur   = (int*)          alloc((size_t)NBUCK2 * sizeof(int));
    short*         WT     = (short*)        alloc((size_t)5 * DIM * DIM * sizeof(short));
    float*         pooled = (float*)        alloc((size_t)NGRAPH * DIM * sizeof(float));

    // ---- prep + CSR build ----
    k_prep   <<<(5 * 16384 + 255) / 256, 256, 0, stream>>>(enc_W1, enc_W2, gcn_W,
                                                           WT, gcur, pooled);
    k_scatter<<<SBLOCKS, 512, 0, stream>>>(src, dst, gcur, tmp);
    k_build  <<<NBUILD, 512, 0, stream>>>(tmp, gcur, row_off, cntA, inv, col);

    // ---- fused encoder: x -> g0 (fp8, pre-scaled by inv) ----
    k_enc<<<EBLOCKS, 512, 0, stream>>>(x, WT, enc_b1, enc_b2, inv, g8a, NNODES);

    // ---- GCN layers: fused agg+gemm (ping-pong g8), last layer agg+pool ----
    k_agg_gemm<<<AGGBLK, 512, 0, stream>>>(g8a, row_off, cntA, col, inv,
                                           gcn_b,       WT + 3 * 16384, g8b);
    k_agg_gemm<<<AGGBLK, 512, 0, stream>>>(g8b, row_off, cntA, col, inv,
                                           gcn_b + 128, WT + 4 * 16384, g8a);
    k_agg_pool<<<AGGBLK, 512, 0, stream>>>(g8a, row_off, cntA, col, inv,
                                           gcn_b + 256, batch, pooled);

    // ---- decoder ----
    k_dec <<<NGRAPH / 8, 512, 0, stream>>>(pooled, dec_W1, dec_b1,
                                           dec_W2, dec_b2, out);
}